// Round 3
// baseline (287.919 us; speedup 1.0000x reference)
//
#include <hip/hip_runtime.h>
#include <cstdint>
#include <cstddef>

#define B_SZ   8
#define SEQ    4096
#define HID    1024
#define NCH    16        // snn time chunks
#define CHUNK  256       // SEQ / NCH
#define WARM   320       // warm-up steps (multiple of 64 when combined: lens 256/512/576 all %64==0)
#define JTAP   16        // truncated SSM impulse-response taps
#define TS     128       // yout t-tile

// ws layout: spk at offset 0, u64 spk[B_SZ*16*SEQ] = 4 MB
__device__ __forceinline__ void snn_step(float& v, float& r, float xv, bool& s) {
  // match reference rounding: separate mul + add (no FMA contraction)
  v = __fadd_rn(__fmul_rn(v, 0.9f), xv);
  s = (r <= 0.0f) && (v >= 1.0f);
  v = s ? 0.0f : v;
  r = s ? 5.0f : fmaxf(r - 1.0f, 0.0f);
}

__device__ __forceinline__ void proc32_emit(const float* xv, float& v, float& r, int lane,
                                            unsigned long long* __restrict__ sp, int t) {
  unsigned long long my = 0;
  #pragma unroll
  for (int k = 0; k < 32; ++k) {
    bool s; snn_step(v, r, xv[k], s);
    unsigned long long m = __ballot(s);
    my = ((lane & 31) == k) ? m : my;
  }
  if (lane < 32) sp[t + lane] = my;     // 256B coalesced burst per 32 steps
}

__device__ __forceinline__ void proc32_warm(const float* xv, float& v, float& r) {
  #pragma unroll
  for (int k = 0; k < 32; ++k) { bool s; snn_step(v, r, xv[k], s); }
}

// Phase 1: LIF scan, chunked in time with bit-exact warm-up restart.
// grid = (HID/256, B_SZ, NCH), block = 256. Batch-32 double-buffered loads:
// 32 loads in flight per wave while 32 steps compute.
__global__ __launch_bounds__(256) void snn_kernel(const float* __restrict__ x,
                                                  unsigned long long* __restrict__ spk) {
  const int hid  = blockIdx.x * 256 + threadIdx.x;
  const int b    = blockIdx.y;
  const int c    = blockIdx.z;
  const int lane = threadIdx.x & 63;
  const int wv   = hid >> 6;                 // global hid-wave index 0..15
  const int t0   = c * CHUNK;
  const int t1   = t0 + CHUNK;
  const int tw   = (t0 >= WARM) ? (t0 - WARM) : 0;  // len(t1-tw) in {256,512,576}, all %64==0
  const float* __restrict__ xp = x + (size_t)(b * SEQ) * HID + hid;
  unsigned long long* __restrict__ sp = spk + (size_t)(b * 16 + wv) * SEQ;

  float v = 0.0f, r = 0.0f;
  float xa[32], xb[32];

  #pragma unroll
  for (int k = 0; k < 32; ++k) xa[k] = xp[(size_t)(tw + k) * HID];

  for (int t = tw; t < t1; t += 64) {
    // prefetch batch B while processing A
    #pragma unroll
    for (int k = 0; k < 32; ++k) xb[k] = xp[(size_t)(t + 32 + k) * HID];

    if (t >= t0) proc32_emit(xa, v, r, lane, sp, t);
    else         proc32_warm(xa, v, r);

    // prefetch next batch A while processing B
    if (t + 64 < t1) {
      #pragma unroll
      for (int k = 0; k < 32; ++k) xa[k] = xp[(size_t)(t + 64 + k) * HID];
    }

    if (t + 32 >= t0) proc32_emit(xb, v, r, lane, sp, t + 32);
    else              proc32_warm(xb, v, r);
  }
}

// Phase 2 (fused): per (b, 128-t tile): wave0 computes w_m = C.A^m.B (Krylov)
// while waves 1-3 stage spk masks into LDS; then u popcounts, y conv, and the
// 134 MB out stream-write. grid = (SEQ/TS, B_SZ), block = 256.
__global__ __launch_bounds__(256) void yout_kernel(const unsigned long long* __restrict__ spk,
                                                   const float* __restrict__ A,
                                                   const float* __restrict__ Bv,
                                                   const float* __restrict__ Cv,
                                                   const float* __restrict__ Dp,
                                                   float4* __restrict__ out) {
  __shared__ unsigned long long lm[16][TS + JTAP];  // masks for t0-16 .. t0+TS
  __shared__ float ws[JTAP];
  __shared__ float su[TS + JTAP];
  __shared__ float sy[TS];

  const int tid = threadIdx.x;
  const int b   = blockIdx.y;
  const int t0  = blockIdx.x * TS;
  const unsigned long long* __restrict__ sb = spk + (size_t)b * 16 * SEQ;

  if (tid < 64) {
    // wave 0: w_m = C . A^m . B via Krylov iteration (4 acc chains)
    const int lane = tid;
    float arow[64];
    #pragma unroll 8
    for (int s2 = 0; s2 < 64; ++s2) arow[s2] = A[lane * 64 + s2];
    float p = Bv[lane];
    const float cv = Cv[lane];
    for (int m = 0; m < JTAP; ++m) {
      float t = cv * p;
      #pragma unroll
      for (int off = 32; off; off >>= 1) t += __shfl_xor(t, off);
      if (lane == 0) ws[m] = t;
      float n0 = 0.f, n1 = 0.f, n2 = 0.f, n3 = 0.f;
      #pragma unroll
      for (int s2 = 0; s2 < 64; s2 += 4) {
        n0 = fmaf(arow[s2 + 0], __shfl(p, s2 + 0), n0);
        n1 = fmaf(arow[s2 + 1], __shfl(p, s2 + 1), n1);
        n2 = fmaf(arow[s2 + 2], __shfl(p, s2 + 2), n2);
        n3 = fmaf(arow[s2 + 3], __shfl(p, s2 + 3), n3);
      }
      p = (n0 + n1) + (n2 + n3);
    }
  } else {
    // waves 1-3: stage spk tile into LDS
    const int i = tid - 64;                 // 0..191
    if (i < TS + JTAP) {
      const int t = t0 - JTAP + i;
      #pragma unroll
      for (int wv = 0; wv < 16; ++wv)
        lm[wv][i] = (t >= 0) ? sb[(size_t)wv * SEQ + t] : 0ull;
    }
  }
  __syncthreads();

  if (tid < TS + JTAP) {
    int cc = 0;
    #pragma unroll
    for (int wv = 0; wv < 16; ++wv) cc += __popcll(lm[wv][tid]);
    su[tid] = cc * (1.0f / 1024.0f);
  }
  __syncthreads();

  if (tid < TS) {
    float acc = Dp[0] * su[JTAP + tid];
    #pragma unroll
    for (int m = 0; m < JTAP; ++m) acc = fmaf(ws[m], su[JTAP + tid - m], acc);
    sy[tid] = acc;
  }
  __syncthreads();

  // stream-write out: TS timesteps x 1024 hid, float4 per thread per step
  const int wv = tid >> 4;
  const int sh = (tid & 15) * 4;
  float4* op = out + (size_t)(b * SEQ + t0) * 256 + tid;
  #pragma unroll 4
  for (int j = 0; j < TS; ++j) {
    const unsigned long long m = lm[wv][JTAP + j];
    const float yv = sy[j];
    float4 o;
    o.x = ((m >> (sh + 0)) & 1ull) ? 1.0f + yv : yv;
    o.y = ((m >> (sh + 1)) & 1ull) ? 1.0f + yv : yv;
    o.z = ((m >> (sh + 2)) & 1ull) ? 1.0f + yv : yv;
    o.w = ((m >> (sh + 3)) & 1ull) ? 1.0f + yv : yv;
    op[(size_t)j * 256] = o;
  }
}

extern "C" void kernel_launch(void* const* d_in, const int* in_sizes, int n_in,
                              void* d_out, int out_size, void* d_ws, size_t ws_size,
                              hipStream_t stream) {
  const float* x  = (const float*)d_in[0];   // (8, 4096, 1024)
  const float* A  = (const float*)d_in[1];   // (64, 64)
  const float* Bv = (const float*)d_in[2];   // (64, 1)
  const float* Cv = (const float*)d_in[3];   // (1, 64)
  const float* Dp = (const float*)d_in[4];   // (1, 1)

  unsigned long long* spk = (unsigned long long*)d_ws;   // 4 MB

  dim3 g1(HID / 256, B_SZ, NCH);
  snn_kernel<<<g1, 256, 0, stream>>>(x, spk);

  dim3 g2(SEQ / TS, B_SZ);
  yout_kernel<<<g2, 256, 0, stream>>>(spk, A, Bv, Cv, Dp, (float4*)d_out);
}

// Round 5
// 283.217 us; speedup vs baseline: 1.0166x; 1.0166x over previous
//
#include <hip/hip_runtime.h>
#include <cstdint>
#include <cstddef>

#define B_SZ   8
#define SEQ    4096
#define HID    1024
#define NCH    8         // snn time chunks
#define CHUNK  512       // SEQ / NCH
#define WARM   256       // warm-up steps; 0.9^256 contraction + spike-reset collapse => bit-exact
#define JTAP   16        // truncated SSM impulse-response taps
#define TS     32        // yout t-tile

typedef float vfloat4 __attribute__((ext_vector_type(4)));   // clang vector: valid for nontemporal builtins

// ws layout: u64 spk[B_SZ*16*SEQ] = 4 MB at offset 0
__device__ __forceinline__ void snn_step(float& v, float& r, float xv, bool& s) {
  // match reference rounding: separate mul + add (no FMA contraction)
  v = __fadd_rn(__fmul_rn(v, 0.9f), xv);
  s = (r <= 0.0f) && (v >= 1.0f);
  v = s ? 0.0f : v;
  r = s ? 5.0f : fmaxf(r - 1.0f, 0.0f);
}

__device__ __forceinline__ void proc32_emit(const float* xv, float& v, float& r, int lane,
                                            unsigned long long* __restrict__ sp, int t) {
  unsigned long long my = 0;
  #pragma unroll
  for (int k = 0; k < 32; ++k) {
    bool s; snn_step(v, r, xv[k], s);
    unsigned long long m = __ballot(s);
    my = ((lane & 31) == k) ? m : my;
  }
  if (lane < 32) sp[t + lane] = my;     // 256B coalesced burst per 32 steps
}

__device__ __forceinline__ void proc32_warm(const float* xv, float& v, float& r) {
  #pragma unroll
  for (int k = 0; k < 32; ++k) { bool s; snn_step(v, r, xv[k], s); }
}

// Phase 1: LIF scan, chunked in time with bit-exact warm-up restart.
// grid = (HID/256, B_SZ, NCH) = 256 blocks (1/CU), block = 256.
// Issued reads: (512 + 7*768)*8192 cols * 4B = 193 MB (was 302).
__global__ __launch_bounds__(256) void snn_kernel(const float* __restrict__ x,
                                                  unsigned long long* __restrict__ spk) {
  const int hid  = blockIdx.x * 256 + threadIdx.x;
  const int b    = blockIdx.y;
  const int c    = blockIdx.z;
  const int lane = threadIdx.x & 63;
  const int wv   = hid >> 6;                 // global hid-wave index 0..15
  const int t0   = c * CHUNK;
  const int t1   = t0 + CHUNK;
  const int tw   = (t0 >= WARM) ? (t0 - WARM) : 0;  // len in {512, 768}, %64==0
  const float* __restrict__ xp = x + (size_t)(b * SEQ) * HID + hid;
  unsigned long long* __restrict__ sp = spk + (size_t)(b * 16 + wv) * SEQ;

  float v = 0.0f, r = 0.0f;
  float xa[32], xb[32];

  #pragma unroll
  for (int k = 0; k < 32; ++k) xa[k] = xp[(size_t)(tw + k) * HID];

  for (int t = tw; t < t1; t += 64) {
    // prefetch batch B while processing A
    #pragma unroll
    for (int k = 0; k < 32; ++k) xb[k] = xp[(size_t)(t + 32 + k) * HID];

    if (t >= t0) proc32_emit(xa, v, r, lane, sp, t);
    else         proc32_warm(xa, v, r);

    // prefetch next batch A while processing B
    if (t + 64 < t1) {
      #pragma unroll
      for (int k = 0; k < 32; ++k) xa[k] = xp[(size_t)(t + 64 + k) * HID];
    }

    if (t + 32 >= t0) proc32_emit(xb, v, r, lane, sp, t + 32);
    else              proc32_warm(xb, v, r);
  }
}

// Phase 2 (fused, small tiles): grid = (SEQ/TS, B_SZ) = 1024 blocks (4/CU).
// wave0 computes w_m = C.A^m.B (redundantly per block, overlapped with staging
// by waves 1-3); then u popcounts, 16-tap conv, and nontemporal stream-out.
__global__ __launch_bounds__(256) void yout_kernel(const unsigned long long* __restrict__ spk,
                                                   const float* __restrict__ A,
                                                   const float* __restrict__ Bv,
                                                   const float* __restrict__ Cv,
                                                   const float* __restrict__ Dp,
                                                   vfloat4* __restrict__ out) {
  __shared__ unsigned long long lm[16][TS + JTAP];  // masks for t0-16 .. t0+TS  (6 KB)
  __shared__ float ws[JTAP];
  __shared__ float su[TS + JTAP];
  __shared__ float sy[TS];

  const int tid = threadIdx.x;
  const int b   = blockIdx.y;
  const int t0  = blockIdx.x * TS;
  const unsigned long long* __restrict__ sb = spk + (size_t)b * 16 * SEQ;

  if (tid < 64) {
    // wave 0: w_m = C . A^m . B via Krylov iteration
    const int lane = tid;
    float arow[64];
    #pragma unroll 8
    for (int s2 = 0; s2 < 64; ++s2) arow[s2] = A[lane * 64 + s2];
    float p = Bv[lane];
    const float cv = Cv[lane];
    for (int m = 0; m < JTAP; ++m) {
      float t = cv * p;
      #pragma unroll
      for (int off = 32; off; off >>= 1) t += __shfl_xor(t, off);
      if (lane == 0) ws[m] = t;
      float n0 = 0.f, n1 = 0.f, n2 = 0.f, n3 = 0.f;
      #pragma unroll
      for (int s2 = 0; s2 < 64; s2 += 4) {
        n0 = fmaf(arow[s2 + 0], __shfl(p, s2 + 0), n0);
        n1 = fmaf(arow[s2 + 1], __shfl(p, s2 + 1), n1);
        n2 = fmaf(arow[s2 + 2], __shfl(p, s2 + 2), n2);
        n3 = fmaf(arow[s2 + 3], __shfl(p, s2 + 3), n3);
      }
      p = (n0 + n1) + (n2 + n3);
    }
  } else {
    // waves 1-3: stage spk tile into LDS
    const int i = tid - 64;                 // 0..191
    if (i < TS + JTAP) {
      const int t = t0 - JTAP + i;
      #pragma unroll
      for (int wv = 0; wv < 16; ++wv)
        lm[wv][i] = (t >= 0) ? sb[(size_t)wv * SEQ + t] : 0ull;
    }
  }
  __syncthreads();

  if (tid < TS + JTAP) {
    int cc = 0;
    #pragma unroll
    for (int wv = 0; wv < 16; ++wv) cc += __popcll(lm[wv][tid]);
    su[tid] = cc * (1.0f / 1024.0f);
  }
  __syncthreads();

  if (tid < TS) {
    float acc = Dp[0] * su[JTAP + tid];
    #pragma unroll
    for (int m = 0; m < JTAP; ++m) acc = fmaf(ws[m], su[JTAP + tid - m], acc);
    sy[tid] = acc;
  }
  __syncthreads();

  // stream-write out: TS timesteps x 1024 hid, nontemporal float4 per thread/step
  const int wv = tid >> 4;
  const int sh = (tid & 15) * 4;
  vfloat4* op = out + (size_t)(b * SEQ + t0) * 256 + tid;
  #pragma unroll 8
  for (int j = 0; j < TS; ++j) {
    const unsigned long long m = lm[wv][JTAP + j];
    const float yv = sy[j];
    vfloat4 o;
    o.x = ((m >> (sh + 0)) & 1ull) ? 1.0f + yv : yv;
    o.y = ((m >> (sh + 1)) & 1ull) ? 1.0f + yv : yv;
    o.z = ((m >> (sh + 2)) & 1ull) ? 1.0f + yv : yv;
    o.w = ((m >> (sh + 3)) & 1ull) ? 1.0f + yv : yv;
    __builtin_nontemporal_store(o, &op[(size_t)j * 256]);
  }
}

extern "C" void kernel_launch(void* const* d_in, const int* in_sizes, int n_in,
                              void* d_out, int out_size, void* d_ws, size_t ws_size,
                              hipStream_t stream) {
  const float* x  = (const float*)d_in[0];   // (8, 4096, 1024)
  const float* A  = (const float*)d_in[1];   // (64, 64)
  const float* Bv = (const float*)d_in[2];   // (64, 1)
  const float* Cv = (const float*)d_in[3];   // (1, 64)
  const float* Dp = (const float*)d_in[4];   // (1, 1)

  unsigned long long* spk = (unsigned long long*)d_ws;   // 4 MB

  dim3 g1(HID / 256, B_SZ, NCH);
  snn_kernel<<<g1, 256, 0, stream>>>(x, spk);

  dim3 g2(SEQ / TS, B_SZ);
  yout_kernel<<<g2, 256, 0, stream>>>(spk, A, Bv, Cv, Dp, (vfloat4*)d_out);
}